// Round 13
// baseline (306.636 us; speedup 1.0000x reference)
//
#include <hip/hip_runtime.h>
#include <hip/hip_cooperative_groups.h>

#define N_NODES 100000
#define N_EDGES 400000
#define D 128
#define BN_EPS 1e-5f
#define NTILES 6250    // N_NODES/16
#define NINTS 100032   // padded int count of cnt arrays (400128 B)
#define SCB 196        // coop-scan blocks: ceil(100000/512)

typedef short short8 __attribute__((ext_vector_type(8)));   // 8 bf16 as raw shorts (4 VGPRs)
typedef float f32x4 __attribute__((ext_vector_type(4)));

static __device__ __forceinline__ float bf2f(unsigned short u) {
    unsigned x = ((unsigned)u) << 16;
    return __builtin_bit_cast(float, x);
}
static __device__ __forceinline__ unsigned short f2bf(float f) {
    unsigned x = __builtin_bit_cast(unsigned, f);
    x += 0x7fffu + ((x >> 16) & 1u);   // round-to-nearest-even
    return (unsigned short)(x >> 16);
}
// split f32 into bf16 hi + bf16 lo (a ~= hi + lo, residual ~2^-17 rel)
static __device__ __forceinline__ void splitbf(float a, short& hi, short& lo) {
    unsigned short h = f2bf(a);
    float r = a - bf2f(h);
    hi = (short)h;
    lo = (short)f2bf(r);
}
static __device__ __forceinline__ void split2(float a, float b, unsigned& hiw, unsigned& low) {
    short ha, la, hb, lb;
    splitbf(a, ha, la);
    splitbf(b, hb, lb);
    hiw = (unsigned)(unsigned short)ha | ((unsigned)(unsigned short)hb << 16);
    low = (unsigned)(unsigned short)la | ((unsigned)(unsigned short)lb << 16);
}
// split 8 f32 (two f32x4) -> uint4 hi-plane + uint4 lo-plane (8 bf16 each)
static __device__ __forceinline__ void split8(f32x4 a, f32x4 b, uint4& hi, uint4& lo) {
    unsigned h0, h1, h2, h3, l0, l1, l2, l3;
    split2(a[0], a[1], h0, l0);
    split2(a[2], a[3], h1, l1);
    split2(b[0], b[1], h2, l2);
    split2(b[2], b[3], h3, l3);
    hi = uint4{h0, h1, h2, h3};
    lo = uint4{l0, l1, l2, l3};
}

// ---------------------------------------------------------------- fallback: clean zero-fill of d_out
__global__ void k_zero_out(float* __restrict__ y, int n4) {
    int t = blockIdx.x * blockDim.x + threadIdx.x;
    if (t < n4) ((float4*)y)[t] = float4{0.f, 0.f, 0.f, 0.f};
}

// ---------------------------------------------------------------- degree histograms
__global__ void k_count(const int* __restrict__ src, const int* __restrict__ dst,
                        int* __restrict__ cnt_src, int* __restrict__ cnt_dst) {
    int t = blockIdx.x * blockDim.x + threadIdx.x;
    if (t >= N_EDGES) return;
    atomicAdd(&cnt_src[src[t]], 1);
    atomicAdd(&cnt_dst[dst[t]], 1);
}

// ---------------------------------------------------------------- W frags + zero the count arrays
// (replaces the hipMemsetAsync: grid-stride zero of cnt_src/cnt_dst; k_count is
// stream-ordered after this kernel so the zeroing is visible to its atomics)
__global__ void k_make_frags(const float* __restrict__ W,
                             const float* __restrict__ Wr,
                             unsigned short* __restrict__ Whi, unsigned short* __restrict__ Wlo,
                             unsigned short* __restrict__ Wrhi, unsigned short* __restrict__ Wrlo,
                             int* __restrict__ cnt_src, int* __restrict__ cnt_dst) {
    int t = blockIdx.x * blockDim.x + threadIdx.x;   // grid 512*256 = 131072
    for (int i = t; i < NINTS; i += 131072) {
        cnt_src[i] = 0;
        cnt_dst[i] = 0;
    }
    if (t >= 4096) return;
    int mat = t >> 11;
    int fragIdx = (t >> 6) & 31;
    int lane = t & 63;
    int nt = fragIdx >> 2, ks = fragIdx & 3;
    const float* Wsrc = mat ? Wr : W;
    unsigned short* dhi = mat ? Wrhi : Whi;
    unsigned short* dlo = mat ? Wrlo : Wlo;
    int n = nt * 16 + (lane & 15);
    int kbase = ks * 32 + (lane >> 4) * 8;
    short hi[8], lo[8];
#pragma unroll
    for (int j = 0; j < 8; j++) splitbf(Wsrc[(kbase + j) * D + n], hi[j], lo[j]);
    ((uint4*)dhi)[fragIdx * 64 + lane] = *(uint4*)hi;
    ((uint4*)dlo)[fragIdx * 64 + lane] = *(uint4*)lo;
}

// ---------------------------------------------------------------- COOP: full exclusive scan + coeffs + BN-zero
// One kernel replaces scan1+scan2+scan3 (2 grid syncs). 196 blocks x 512 threads.
__global__ void k_scan_all(const int* __restrict__ cnt_dst, int* __restrict__ rowStart,
                           int* __restrict__ bsum,
                           const int* __restrict__ cnt_src,
                           float* __restrict__ c_src, float* __restrict__ c_dst,
                           int* __restrict__ fill,
                           float* __restrict__ gsum, float* __restrict__ gsq) {
    __shared__ int s[512];
    const int i = blockIdx.x * 512 + threadIdx.x;
    int v = (i < N_NODES) ? cnt_dst[i] : 0;
    if (i < N_NODES) {
        c_src[i] = rsqrtf(fmaxf((float)cnt_src[i], 1.0f));
        c_dst[i] = rsqrtf(fmaxf((float)v, 1.0f));
        fill[i] = 0;
    }
    if (i < 128) { gsum[i] = 0.f; gsq[i] = 0.f; }
    s[threadIdx.x] = v;
    __syncthreads();
    for (int d = 1; d < 512; d <<= 1) {
        int t = (threadIdx.x >= d) ? s[threadIdx.x - d] : 0;
        __syncthreads();
        s[threadIdx.x] += t;
        __syncthreads();
    }
    if (i < N_NODES) rowStart[i] = s[threadIdx.x] - v;   // exclusive, intra-block
    if (threadIdx.x == 511) bsum[blockIdx.x] = s[511];
    cooperative_groups::this_grid().sync();
    // phase 2: block 0 exclusive-scans the 196 block sums
    if (blockIdx.x == 0) {
        int v2 = (threadIdx.x < SCB) ? bsum[threadIdx.x] : 0;
        __syncthreads();
        s[threadIdx.x] = v2;
        __syncthreads();
        for (int d = 1; d < 512; d <<= 1) {
            int t = (threadIdx.x >= d) ? s[threadIdx.x - d] : 0;
            __syncthreads();
            s[threadIdx.x] += t;
            __syncthreads();
        }
        if (threadIdx.x < SCB) bsum[threadIdx.x] = s[threadIdx.x] - v2;
    }
    cooperative_groups::this_grid().sync();
    // phase 3: add block offsets
    if (i < N_NODES) rowStart[i] += bsum[i >> 9];
    if (i == 0) rowStart[N_NODES] = N_EDGES;
}

// ---------------------------------------------------------------- fallback scan path (3 kernels)
__global__ void k_scan1(const int* __restrict__ cnt, int* __restrict__ outp,
                        int* __restrict__ bsum,
                        const int* __restrict__ cnt_src,
                        float* __restrict__ c_src, float* __restrict__ c_dst,
                        int* __restrict__ fill,
                        float* __restrict__ gsum, float* __restrict__ gsq) {
    __shared__ int s[256];
    int i = blockIdx.x * 256 + threadIdx.x;
    int v = (i < N_NODES) ? cnt[i] : 0;
    if (i < N_NODES) {
        c_src[i] = rsqrtf(fmaxf((float)cnt_src[i], 1.0f));
        c_dst[i] = rsqrtf(fmaxf((float)v, 1.0f));
        fill[i] = 0;
    }
    if (i < 128) { gsum[i] = 0.f; gsq[i] = 0.f; }
    s[threadIdx.x] = v;
    __syncthreads();
    for (int d = 1; d < 256; d <<= 1) {
        int t = (threadIdx.x >= d) ? s[threadIdx.x - d] : 0;
        __syncthreads();
        s[threadIdx.x] += t;
        __syncthreads();
    }
    if (i < N_NODES) outp[i] = s[threadIdx.x] - v;   // exclusive
    if (threadIdx.x == 255) bsum[blockIdx.x] = s[255];
}

__global__ void k_scan2(int* __restrict__ bsum, int nb) {
    __shared__ int s[512];
    int v = (threadIdx.x < nb) ? bsum[threadIdx.x] : 0;
    s[threadIdx.x] = v;
    __syncthreads();
    for (int d = 1; d < 512; d <<= 1) {
        int t = (threadIdx.x >= d) ? s[threadIdx.x - d] : 0;
        __syncthreads();
        s[threadIdx.x] += t;
        __syncthreads();
    }
    if (threadIdx.x < nb) bsum[threadIdx.x] = s[threadIdx.x] - v;
}

__global__ void k_scan3(int* __restrict__ rowStart, const int* __restrict__ boff) {
    int i = blockIdx.x * 256 + threadIdx.x;
    if (i < N_NODES) rowStart[i] += boff[i >> 8];
    if (i == 0) rowStart[N_NODES] = N_EDGES;
}

// ---------------------------------------------------------------- bucket-fill: edge srcs sorted by dst
__global__ void k_fill(const int* __restrict__ src, const int* __restrict__ dst,
                       const int* __restrict__ rowStart, int* __restrict__ fill,
                       int* __restrict__ esorted) {
    int e = blockIdx.x * blockDim.x + threadIdx.x;
    if (e >= N_EDGES) return;
    int d = dst[e];
    int pos = rowStart[d] + atomicAdd(&fill[d], 1);
    esorted[pos] = src[e];
}

// ---------------------------------------------------------------- FUSED gather + dual GEMM  (r12 verbatim)
// 77 µs, FETCH 127 MB, WRITE 51 MB, VGPR 128, LDS 32768, no spills. Residency is
// VGPR+AGPR-tier-capped at 2 blocks/CU (r7/r12: grid and LDS changes are no-ops).
// Chunk-8 gather, SHORT-LIVED row regs (r9/r10: anything held across MFMA spills).
// Double-buffered A-tile, ONE barrier/tile; direct global epilogue stores.
// DO NOT raise launch_bounds min-waves (r6: weight-set eviction).
__global__ __launch_bounds__(256, 2) void k_fused(
    const float* __restrict__ x,
    const int* __restrict__ esorted, const int* __restrict__ rowStart,
    const float* __restrict__ c_src, const float* __restrict__ c_dst,
    const unsigned short* __restrict__ Whi, const unsigned short* __restrict__ Wlo,
    const unsigned short* __restrict__ Wrhi, const unsigned short* __restrict__ Wrlo,
    const float* __restrict__ bias_h, const float* __restrict__ bias_r,
    float* __restrict__ yout,
    float* __restrict__ gsum, float* __restrict__ gsq) {
    __shared__ uint4 A[2][16][64];    // 32 KB double-buffered A-tile

    const int wave = threadIdx.x >> 6;
    const int lane = threadIdx.x & 63;
    const int quad = lane >> 4;
    const int l16 = lane & 15;

    // ---- preload this wave's 32-col weight frags into VGPRs (128 VGPR)
    short8 wHf[8], wLf[8], rHf[8], rLf[8];
#pragma unroll
    for (int f = 0; f < 8; f++) {
        int nt = wave * 2 + (f >> 2), ks = f & 3;
        int gi = (nt * 4 + ks) * 64 + lane;
        wHf[f] = __builtin_bit_cast(short8, ((const uint4*)Whi)[gi]);
        wLf[f] = __builtin_bit_cast(short8, ((const uint4*)Wlo)[gi]);
        rHf[f] = __builtin_bit_cast(short8, ((const uint4*)Wrhi)[gi]);
        rLf[f] = __builtin_bit_cast(short8, ((const uint4*)Wrlo)[gi]);
    }
    float bh[2], brr[2];
#pragma unroll
    for (int ntl = 0; ntl < 2; ntl++) {
        int col = wave * 32 + ntl * 16 + l16;
        bh[ntl] = bias_h[col];
        brr[ntl] = bias_r[col];
    }

    float s_acc[2] = {0.f, 0.f}, q_acc[2] = {0.f, 0.f};
    const f32x4* __restrict__ xb = (const f32x4*)x;   // 32 f32x4 per node row

    int buf = 0;
    for (int rt = blockIdx.x; rt < NTILES; rt += gridDim.x, buf ^= 1) {
        const int rowbase = rt * 16;

        // ================= phase A: quad-gather node rowbase + wave*4 + quad (chunk-8)
        {
            const int R = wave * 4 + quad;          // row within tile
            const int n = rowbase + R;
            const int li = l16;                     // feature octet index
            const int beg = rowStart[n], end = rowStart[n + 1];
            // residual x-row: issue first so it's in flight under the edge loop
            f32x4 X0 = xb[(size_t)n * 32 + li * 2], X1 = xb[(size_t)n * 32 + li * 2 + 1];
            f32x4 A0 = {0.f, 0.f, 0.f, 0.f}, A1 = {0.f, 0.f, 0.f, 0.f};
            for (int j = beg; j < end; j += 8) {
                int idx[8];
                float c[8];
                f32x4 pa[8], pb[8];
#pragma unroll
                for (int k = 0; k < 8; k++) {
                    int jj = j + k;
                    idx[k] = esorted[(jj < end) ? jj : j];   // dup edge-0 pad (cache hit)
                }
#pragma unroll
                for (int k = 0; k < 8; k++)
                    c[k] = (j + k < end) ? c_src[idx[k]] : 0.f;
                // 16 independent 16B loads in flight -> one HBM latency per round
#pragma unroll
                for (int k = 0; k < 8; k++) {
                    pa[k] = xb[(size_t)idx[k] * 32 + li * 2];
                    pb[k] = xb[(size_t)idx[k] * 32 + li * 2 + 1];
                }
#pragma unroll
                for (int k = 0; k < 8; k++) {
                    A0 += pa[k] * c[k];
                    A1 += pb[k] * c[k];
                }
            }
            float cd = c_dst[n];
            A0 *= cd; A1 *= cd;
            uint4 ahi, alo, xhi, xlo;
            split8(A0, A1, ahi, alo);
            split8(X0, X1, xhi, xlo);
            uint4* Arow = &A[buf][R][0];
            const int sw = li ^ (R & 7);            // bank swizzle
            Arow[sw] = ahi;
            Arow[16 + sw] = alo;
            Arow[32 + sw] = xhi;
            Arow[48 + sw] = xlo;
        }
        __syncthreads();   // A-tile writes visible; double-buffer -> only barrier needed

        // ================= phase B: MFMA from LDS A-tile
        const uint4* rowA = &A[buf][l16][0];
        const int r7 = l16 & 7;
        short8 aH[4], aL[4], xH[4], xL[4];
#pragma unroll
        for (int ks = 0; ks < 4; ks++) {
            const int sl = (ks * 4 + quad) ^ r7;
            aH[ks] = __builtin_bit_cast(short8, rowA[sl]);
            aL[ks] = __builtin_bit_cast(short8, rowA[16 + sl]);
            xH[ks] = __builtin_bit_cast(short8, rowA[32 + sl]);
            xL[ks] = __builtin_bit_cast(short8, rowA[48 + sl]);
        }

        f32x4 accH[2], accR[2];
#pragma unroll
        for (int ntl = 0; ntl < 2; ntl++) {
            accH[ntl] = f32x4{0.f, 0.f, 0.f, 0.f};
            accR[ntl] = f32x4{0.f, 0.f, 0.f, 0.f};
#pragma unroll
            for (int ks = 0; ks < 4; ks++) {
                const int f = ntl * 4 + ks;
                accH[ntl] = __builtin_amdgcn_mfma_f32_16x16x32_bf16(aH[ks], wHf[f], accH[ntl], 0, 0, 0);
                accH[ntl] = __builtin_amdgcn_mfma_f32_16x16x32_bf16(aH[ks], wLf[f], accH[ntl], 0, 0, 0);
                accH[ntl] = __builtin_amdgcn_mfma_f32_16x16x32_bf16(aL[ks], wHf[f], accH[ntl], 0, 0, 0);
                accR[ntl] = __builtin_amdgcn_mfma_f32_16x16x32_bf16(xH[ks], rHf[f], accR[ntl], 0, 0, 0);
                accR[ntl] = __builtin_amdgcn_mfma_f32_16x16x32_bf16(xH[ks], rLf[f], accR[ntl], 0, 0, 0);
                accR[ntl] = __builtin_amdgcn_mfma_f32_16x16x32_bf16(xL[ks], rHf[f], accR[ntl], 0, 0, 0);
            }
        }

        // ---- epilogue: DIRECT global stores from acc + BN partials (no LDS, no waits)
#pragma unroll
        for (int ntl = 0; ntl < 2; ntl++) {
            float s = 0.f, q = 0.f;
#pragma unroll
            for (int r = 0; r < 4; r++) {
                float y = fmaxf(accH[ntl][r] + bh[ntl], 0.f) + fmaxf(accR[ntl][r] + brr[ntl], 0.f);
                yout[(size_t)(rowbase + quad * 4 + r) * D + wave * 32 + ntl * 16 + l16] = y;
                s += y;
                q += y * y;
            }
            s_acc[ntl] += s;
            q_acc[ntl] += q;
        }
        // no trailing barrier: next iter writes A[buf^1]; per-iter barrier keeps all
        // waves within one iteration, so A[buf] reads finish before its next write
    }

    // ---- per-wave stats: quads hold same column set
#pragma unroll
    for (int ntl = 0; ntl < 2; ntl++) {
        float s = s_acc[ntl], q = q_acc[ntl];
        s += __shfl_xor(s, 16, 64);
        s += __shfl_xor(s, 32, 64);
        q += __shfl_xor(q, 16, 64);
        q += __shfl_xor(q, 32, 64);
        if (lane < 16) {
            unsafeAtomicAdd(&gsum[wave * 32 + ntl * 16 + lane], s);
            unsafeAtomicAdd(&gsq[wave * 32 + ntl * 16 + lane], q);
        }
    }
}

// ---------------------------------------------------------------- BN stats + apply, merged
__global__ void k_bn_apply(float* __restrict__ y,
                           const float* __restrict__ gsum, const float* __restrict__ gsq,
                           const float* __restrict__ gamma, const float* __restrict__ beta) {
    __shared__ float sc[128], sh[128];
    if (threadIdx.x < 128) {
        int f = threadIdx.x;
        const float invN = 1.0f / (float)N_NODES;
        float mean = gsum[f] * invN;
        float var = fmaxf(gsq[f] * invN - mean * mean, 0.f);
        float s = gamma[f] * rsqrtf(var + BN_EPS);
        sc[f] = s;
        sh[f] = beta[f] - mean * s;
    }
    __syncthreads();
    const int total4 = N_NODES * D / 4;
    for (int i = blockIdx.x * blockDim.x + threadIdx.x; i < total4; i += gridDim.x * blockDim.x) {
        float4 v = ((float4*)y)[i];
        int f = (i * 4) & (D - 1);
        v.x = v.x * sc[f] + sh[f];
        v.y = v.y * sc[f + 1] + sh[f + 1];
        v.z = v.z * sc[f + 2] + sh[f + 2];
        v.w = v.w * sc[f + 3] + sh[f + 3];
        ((float4*)y)[i] = v;
    }
}

// ---------------------------------------------------------------- launch
extern "C" void kernel_launch(void* const* d_in, const int* in_sizes, int n_in,
                              void* d_out, int out_size, void* d_ws, size_t ws_size,
                              hipStream_t stream) {
    const float* x     = (const float*)d_in[0];   // node_feats f32 [N,128]
    const float* W     = (const float*)d_in[1];
    const float* b     = (const float*)d_in[2];
    const float* Wr    = (const float*)d_in[3];
    const float* br    = (const float*)d_in[4];
    const float* gamma = (const float*)d_in[5];
    const float* beta  = (const float*)d_in[6];
    const int* src = (const int*)d_in[7];
    const int* dst = (const int*)d_in[8];
    float* out = (float*)d_out;

    const int NB1 = (N_NODES + 255) / 256;   // 391 fallback-scan blocks

    char* ws = (char*)d_ws;
    size_t off = 0;
    float* gsum    = (float*)(ws + off); off += 512;
    float* gsq     = (float*)(ws + off); off += 512;
    int* cnt_src   = (int*)(ws + off); off += 400128;   // NINTS*4
    int* cnt_dst   = (int*)(ws + off); off += 400128;
    int* fill      = (int*)(ws + off); off += 400128;   // zeroed by scan kernels
    int* rowStart  = (int*)(ws + off); off += 400384;   // (N+1)*4 padded
    int* bsum      = (int*)(ws + off); off += 2048;
    int* esorted   = (int*)(ws + off); off += (size_t)N_EDGES * 4;   // 1.6 MB
    float* c_src   = (float*)(ws + off); off += 400128;
    float* c_dst   = (float*)(ws + off); off += 400128;
    unsigned short* WhiF  = (unsigned short*)(ws + off); off += 32768;
    unsigned short* WloF  = (unsigned short*)(ws + off); off += 32768;
    unsigned short* WrhiF = (unsigned short*)(ws + off); off += 32768;
    unsigned short* WrloF = (unsigned short*)(ws + off); off += 32768;
    const size_t needed = off;   // ~4.3 MB

    if (ws_size < needed) {
        k_zero_out<<<(N_NODES * D / 4 + 255) / 256, 256, 0, stream>>>(out, N_NODES * D / 4);
        return;
    }

    // 1. weight frags + zero count arrays (replaces hipMemsetAsync)
    k_make_frags<<<512, 256, 0, stream>>>(W, Wr, WhiF, WloF, WrhiF, WrloF, cnt_src, cnt_dst);
    // 2. degree histograms
    k_count<<<(N_EDGES + 255) / 256, 256, 0, stream>>>(src, dst, cnt_src, cnt_dst);
    // 3. full scan + coeffs + BN-zero in ONE cooperative kernel (fallback: 3 kernels)
    {
        void* sargs[] = {
            (void*)&cnt_dst, (void*)&rowStart, (void*)&bsum, (void*)&cnt_src,
            (void*)&c_src, (void*)&c_dst, (void*)&fill, (void*)&gsum, (void*)&gsq
        };
        hipError_t ce = hipLaunchCooperativeKernel((const void*)k_scan_all, dim3(SCB), dim3(512),
                                                   sargs, 0, stream);
        if (ce != hipSuccess) {
            (void)hipGetLastError();   // clear error state
            k_scan1<<<NB1, 256, 0, stream>>>(cnt_dst, rowStart, bsum, cnt_src,
                                             c_src, c_dst, fill, gsum, gsq);
            k_scan2<<<1, 512, 0, stream>>>(bsum, NB1);
            k_scan3<<<NB1, 256, 0, stream>>>(rowStart, bsum);
        }
    }
    // 4. bucket-fill edges by dst
    k_fill<<<(N_EDGES + 255) / 256, 256, 0, stream>>>(src, dst, rowStart, fill, esorted);
    // 5. fused gather (chunk-8) + dual GEMM + relu + add + BN partials
    k_fused<<<1024, 256, 0, stream>>>(x, esorted, rowStart, c_src, c_dst,
                                      WhiF, WloF, WrhiF, WrloF, b, br, out, gsum, gsq);
    // 6. BN stats + apply (merged)
    k_bn_apply<<<2048, 256, 0, stream>>>(out, gsum, gsq, gamma, beta);
}

// Round 14
// 248.992 us; speedup vs baseline: 1.2315x; 1.2315x over previous
//
#include <hip/hip_runtime.h>

#define N_NODES 100000
#define N_EDGES 400000
#define D 128
#define BN_EPS 1e-5f
#define NTILES 6250   // N_NODES/16

typedef short short8 __attribute__((ext_vector_type(8)));   // 8 bf16 as raw shorts (4 VGPRs)
typedef float f32x4 __attribute__((ext_vector_type(4)));

static __device__ __forceinline__ float bf2f(unsigned short u) {
    unsigned x = ((unsigned)u) << 16;
    return __builtin_bit_cast(float, x);
}
static __device__ __forceinline__ unsigned short f2bf(float f) {
    unsigned x = __builtin_bit_cast(unsigned, f);
    x += 0x7fffu + ((x >> 16) & 1u);   // round-to-nearest-even
    return (unsigned short)(x >> 16);
}
// split f32 into bf16 hi + bf16 lo (a ~= hi + lo, residual ~2^-17 rel)
static __device__ __forceinline__ void splitbf(float a, short& hi, short& lo) {
    unsigned short h = f2bf(a);
    float r = a - bf2f(h);
    hi = (short)h;
    lo = (short)f2bf(r);
}
static __device__ __forceinline__ void split2(float a, float b, unsigned& hiw, unsigned& low) {
    short ha, la, hb, lb;
    splitbf(a, ha, la);
    splitbf(b, hb, lb);
    hiw = (unsigned)(unsigned short)ha | ((unsigned)(unsigned short)hb << 16);
    low = (unsigned)(unsigned short)la | ((unsigned)(unsigned short)lb << 16);
}
// split 8 f32 (two f32x4) -> uint4 hi-plane + uint4 lo-plane (8 bf16 each)
static __device__ __forceinline__ void split8(f32x4 a, f32x4 b, uint4& hi, uint4& lo) {
    unsigned h0, h1, h2, h3, l0, l1, l2, l3;
    split2(a[0], a[1], h0, l0);
    split2(a[2], a[3], h1, l1);
    split2(b[0], b[1], h2, l2);
    split2(b[2], b[3], h3, l3);
    hi = uint4{h0, h1, h2, h3};
    lo = uint4{l0, l1, l2, l3};
}

// ---------------------------------------------------------------- fallback: clean zero-fill of d_out
__global__ void k_zero_out(float* __restrict__ y, int n4) {
    int t = blockIdx.x * blockDim.x + threadIdx.x;
    if (t < n4) ((float4*)y)[t] = float4{0.f, 0.f, 0.f, 0.f};
}

// ---------------------------------------------------------------- degree histograms
__global__ void k_count(const int* __restrict__ src, const int* __restrict__ dst,
                        int* __restrict__ cnt_src, int* __restrict__ cnt_dst) {
    int t = blockIdx.x * blockDim.x + threadIdx.x;
    if (t >= N_EDGES) return;
    atomicAdd(&cnt_src[src[t]], 1);
    atomicAdd(&cnt_dst[dst[t]], 1);
}

// ---------------------------------------------------------------- exclusive scan level 1 + coeffs (merged)
__global__ void k_scan1(const int* __restrict__ cnt, int* __restrict__ outp,
                        int* __restrict__ bsum,
                        const int* __restrict__ cnt_src,
                        float* __restrict__ c_src, float* __restrict__ c_dst,
                        int* __restrict__ fill) {
    __shared__ int s[256];
    int i = blockIdx.x * 256 + threadIdx.x;
    int v = (i < N_NODES) ? cnt[i] : 0;
    // merged coeffs: rsqrt coefficients + zero the fill cursors
    if (i < N_NODES) {
        c_src[i] = rsqrtf(fmaxf((float)cnt_src[i], 1.0f));
        c_dst[i] = rsqrtf(fmaxf((float)v, 1.0f));
        fill[i] = 0;
    }
    s[threadIdx.x] = v;
    __syncthreads();
    for (int d = 1; d < 256; d <<= 1) {
        int t = (threadIdx.x >= d) ? s[threadIdx.x - d] : 0;
        __syncthreads();
        s[threadIdx.x] += t;
        __syncthreads();
    }
    if (i < N_NODES) outp[i] = s[threadIdx.x] - v;   // exclusive
    if (threadIdx.x == 255) bsum[blockIdx.x] = s[255];
}

// ---------------------------------------------------------------- exclusive scan, level 2 (single block, nb<=512)
__global__ void k_scan2(int* __restrict__ bsum, int nb) {
    __shared__ int s[512];
    int v = (threadIdx.x < nb) ? bsum[threadIdx.x] : 0;
    s[threadIdx.x] = v;
    __syncthreads();
    for (int d = 1; d < 512; d <<= 1) {
        int t = (threadIdx.x >= d) ? s[threadIdx.x - d] : 0;
        __syncthreads();
        s[threadIdx.x] += t;
        __syncthreads();
    }
    if (threadIdx.x < nb) bsum[threadIdx.x] = s[threadIdx.x] - v;
}

// ---------------------------------------------------------------- scan fixup
__global__ void k_scan3(int* __restrict__ rowStart, const int* __restrict__ boff) {
    int i = blockIdx.x * 256 + threadIdx.x;
    if (i < N_NODES) rowStart[i] += boff[i >> 8];
    if (i == 0) rowStart[N_NODES] = N_EDGES;
}

// ---------------------------------------------------------------- bucket-fill: edge srcs sorted by dst
__global__ void k_fill(const int* __restrict__ src, const int* __restrict__ dst,
                       const int* __restrict__ rowStart, int* __restrict__ fill,
                       int* __restrict__ esorted) {
    int e = blockIdx.x * blockDim.x + threadIdx.x;
    if (e >= N_EDGES) return;
    int d = dst[e];
    int pos = rowStart[d] + atomicAdd(&fill[d], 1);
    esorted[pos] = src[e];
}

// ---------------------------------------------------------------- W(f32) -> MFMA B-fragment order, split hi/lo bf16
__global__ void k_make_frags(const float* __restrict__ W,
                             const float* __restrict__ Wr,
                             unsigned short* __restrict__ Whi, unsigned short* __restrict__ Wlo,
                             unsigned short* __restrict__ Wrhi, unsigned short* __restrict__ Wrlo) {
    int t = blockIdx.x * blockDim.x + threadIdx.x;   // 0..4095
    if (t >= 4096) return;
    int mat = t >> 11;
    int fragIdx = (t >> 6) & 31;
    int lane = t & 63;
    int nt = fragIdx >> 2, ks = fragIdx & 3;
    const float* Wsrc = mat ? Wr : W;
    unsigned short* dhi = mat ? Wrhi : Whi;
    unsigned short* dlo = mat ? Wrlo : Wlo;
    int n = nt * 16 + (lane & 15);
    int kbase = ks * 32 + (lane >> 4) * 8;
    short hi[8], lo[8];
#pragma unroll
    for (int j = 0; j < 8; j++) splitbf(Wsrc[(kbase + j) * D + n], hi[j], lo[j]);
    ((uint4*)dhi)[fragIdx * 64 + lane] = *(uint4*)hi;
    ((uint4*)dlo)[fragIdx * 64 + lane] = *(uint4*)lo;
}

// ---------------------------------------------------------------- FUSED gather + dual GEMM  (r12 benched config)
// 76-78 µs, FETCH 127 MB, WRITE 51 MB, VGPR 128, LDS 32768, no spills. Residency is
// VGPR+AGPR-tier-capped at 2 blocks/CU (r7/r12: grid and LDS changes are no-ops).
// Chunk-8 gather, SHORT-LIVED row regs (r9/r10: anything held across MFMA spills).
// Double-buffered A-tile, ONE barrier/tile; direct global epilogue stores.
// DO NOT raise launch_bounds min-waves (r6: weight-set eviction).
// DO NOT use cooperative launch anywhere (r9/r10/r13: −60 µs dispatch overhead).
__global__ __launch_bounds__(256, 2) void k_fused(
    const float* __restrict__ x,
    const int* __restrict__ esorted, const int* __restrict__ rowStart,
    const float* __restrict__ c_src, const float* __restrict__ c_dst,
    const unsigned short* __restrict__ Whi, const unsigned short* __restrict__ Wlo,
    const unsigned short* __restrict__ Wrhi, const unsigned short* __restrict__ Wrlo,
    const float* __restrict__ bias_h, const float* __restrict__ bias_r,
    float* __restrict__ yout,
    float* __restrict__ gsum, float* __restrict__ gsq) {
    __shared__ uint4 A[2][16][64];    // 32 KB double-buffered A-tile

    const int wave = threadIdx.x >> 6;
    const int lane = threadIdx.x & 63;
    const int quad = lane >> 4;
    const int l16 = lane & 15;

    // ---- preload this wave's 32-col weight frags into VGPRs (128 VGPR)
    short8 wHf[8], wLf[8], rHf[8], rLf[8];
#pragma unroll
    for (int f = 0; f < 8; f++) {
        int nt = wave * 2 + (f >> 2), ks = f & 3;
        int gi = (nt * 4 + ks) * 64 + lane;
        wHf[f] = __builtin_bit_cast(short8, ((const uint4*)Whi)[gi]);
        wLf[f] = __builtin_bit_cast(short8, ((const uint4*)Wlo)[gi]);
        rHf[f] = __builtin_bit_cast(short8, ((const uint4*)Wrhi)[gi]);
        rLf[f] = __builtin_bit_cast(short8, ((const uint4*)Wrlo)[gi]);
    }
    float bh[2], brr[2];
#pragma unroll
    for (int ntl = 0; ntl < 2; ntl++) {
        int col = wave * 32 + ntl * 16 + l16;
        bh[ntl] = bias_h[col];
        brr[ntl] = bias_r[col];
    }

    float s_acc[2] = {0.f, 0.f}, q_acc[2] = {0.f, 0.f};
    const f32x4* __restrict__ xb = (const f32x4*)x;   // 32 f32x4 per node row

    int buf = 0;
    for (int rt = blockIdx.x; rt < NTILES; rt += gridDim.x, buf ^= 1) {
        const int rowbase = rt * 16;

        // ================= phase A: quad-gather node rowbase + wave*4 + quad (chunk-8)
        {
            const int R = wave * 4 + quad;          // row within tile
            const int n = rowbase + R;
            const int li = l16;                     // feature octet index
            const int beg = rowStart[n], end = rowStart[n + 1];
            // residual x-row: issue first so it's in flight under the edge loop
            f32x4 X0 = xb[(size_t)n * 32 + li * 2], X1 = xb[(size_t)n * 32 + li * 2 + 1];
            f32x4 A0 = {0.f, 0.f, 0.f, 0.f}, A1 = {0.f, 0.f, 0.f, 0.f};
            for (int j = beg; j < end; j += 8) {
                int idx[8];
                float c[8];
                f32x4 pa[8], pb[8];
#pragma unroll
                for (int k = 0; k < 8; k++) {
                    int jj = j + k;
                    idx[k] = esorted[(jj < end) ? jj : j];   // dup edge-0 pad (cache hit)
                }
#pragma unroll
                for (int k = 0; k < 8; k++)
                    c[k] = (j + k < end) ? c_src[idx[k]] : 0.f;
                // 16 independent 16B loads in flight -> one HBM latency per round
#pragma unroll
                for (int k = 0; k < 8; k++) {
                    pa[k] = xb[(size_t)idx[k] * 32 + li * 2];
                    pb[k] = xb[(size_t)idx[k] * 32 + li * 2 + 1];
                }
#pragma unroll
                for (int k = 0; k < 8; k++) {
                    A0 += pa[k] * c[k];
                    A1 += pb[k] * c[k];
                }
            }
            float cd = c_dst[n];
            A0 *= cd; A1 *= cd;
            uint4 ahi, alo, xhi, xlo;
            split8(A0, A1, ahi, alo);
            split8(X0, X1, xhi, xlo);
            uint4* Arow = &A[buf][R][0];
            const int sw = li ^ (R & 7);            // bank swizzle
            Arow[sw] = ahi;
            Arow[16 + sw] = alo;
            Arow[32 + sw] = xhi;
            Arow[48 + sw] = xlo;
        }
        __syncthreads();   // A-tile writes visible; double-buffer -> only barrier needed

        // ================= phase B: MFMA from LDS A-tile
        const uint4* rowA = &A[buf][l16][0];
        const int r7 = l16 & 7;
        short8 aH[4], aL[4], xH[4], xL[4];
#pragma unroll
        for (int ks = 0; ks < 4; ks++) {
            const int sl = (ks * 4 + quad) ^ r7;
            aH[ks] = __builtin_bit_cast(short8, rowA[sl]);
            aL[ks] = __builtin_bit_cast(short8, rowA[16 + sl]);
            xH[ks] = __builtin_bit_cast(short8, rowA[32 + sl]);
            xL[ks] = __builtin_bit_cast(short8, rowA[48 + sl]);
        }

        f32x4 accH[2], accR[2];
#pragma unroll
        for (int ntl = 0; ntl < 2; ntl++) {
            accH[ntl] = f32x4{0.f, 0.f, 0.f, 0.f};
            accR[ntl] = f32x4{0.f, 0.f, 0.f, 0.f};
#pragma unroll
            for (int ks = 0; ks < 4; ks++) {
                const int f = ntl * 4 + ks;
                accH[ntl] = __builtin_amdgcn_mfma_f32_16x16x32_bf16(aH[ks], wHf[f], accH[ntl], 0, 0, 0);
                accH[ntl] = __builtin_amdgcn_mfma_f32_16x16x32_bf16(aH[ks], wLf[f], accH[ntl], 0, 0, 0);
                accH[ntl] = __builtin_amdgcn_mfma_f32_16x16x32_bf16(aL[ks], wHf[f], accH[ntl], 0, 0, 0);
                accR[ntl] = __builtin_amdgcn_mfma_f32_16x16x32_bf16(xH[ks], rHf[f], accR[ntl], 0, 0, 0);
                accR[ntl] = __builtin_amdgcn_mfma_f32_16x16x32_bf16(xH[ks], rLf[f], accR[ntl], 0, 0, 0);
                accR[ntl] = __builtin_amdgcn_mfma_f32_16x16x32_bf16(xL[ks], rHf[f], accR[ntl], 0, 0, 0);
            }
        }

        // ---- epilogue: DIRECT global stores from acc + BN partials (no LDS, no waits)
#pragma unroll
        for (int ntl = 0; ntl < 2; ntl++) {
            float s = 0.f, q = 0.f;
#pragma unroll
            for (int r = 0; r < 4; r++) {
                float y = fmaxf(accH[ntl][r] + bh[ntl], 0.f) + fmaxf(accR[ntl][r] + brr[ntl], 0.f);
                yout[(size_t)(rowbase + quad * 4 + r) * D + wave * 32 + ntl * 16 + l16] = y;
                s += y;
                q += y * y;
            }
            s_acc[ntl] += s;
            q_acc[ntl] += q;
        }
        // no trailing barrier: next iter writes A[buf^1]; per-iter barrier keeps all
        // waves within one iteration, so A[buf] reads finish before its next write
    }

    // ---- per-wave stats: quads hold same column set
#pragma unroll
    for (int ntl = 0; ntl < 2; ntl++) {
        float s = s_acc[ntl], q = q_acc[ntl];
        s += __shfl_xor(s, 16, 64);
        s += __shfl_xor(s, 32, 64);
        q += __shfl_xor(q, 16, 64);
        q += __shfl_xor(q, 32, 64);
        if (lane < 16) {
            unsafeAtomicAdd(&gsum[wave * 32 + ntl * 16 + lane], s);
            unsafeAtomicAdd(&gsq[wave * 32 + ntl * 16 + lane], q);
        }
    }
}

// ---------------------------------------------------------------- BN stats + apply, merged
__global__ void k_bn_apply(float* __restrict__ y,
                           const float* __restrict__ gsum, const float* __restrict__ gsq,
                           const float* __restrict__ gamma, const float* __restrict__ beta) {
    __shared__ float sc[128], sh[128];
    if (threadIdx.x < 128) {
        int f = threadIdx.x;
        const float invN = 1.0f / (float)N_NODES;
        float mean = gsum[f] * invN;
        float var = fmaxf(gsq[f] * invN - mean * mean, 0.f);
        float s = gamma[f] * rsqrtf(var + BN_EPS);
        sc[f] = s;
        sh[f] = beta[f] - mean * s;
    }
    __syncthreads();
    const int total4 = N_NODES * D / 4;
    for (int i = blockIdx.x * blockDim.x + threadIdx.x; i < total4; i += gridDim.x * blockDim.x) {
        float4 v = ((float4*)y)[i];
        int f = (i * 4) & (D - 1);
        v.x = v.x * sc[f] + sh[f];
        v.y = v.y * sc[f + 1] + sh[f + 1];
        v.z = v.z * sc[f + 2] + sh[f + 2];
        v.w = v.w * sc[f + 3] + sh[f + 3];
        ((float4*)y)[i] = v;
    }
}

// ---------------------------------------------------------------- launch
extern "C" void kernel_launch(void* const* d_in, const int* in_sizes, int n_in,
                              void* d_out, int out_size, void* d_ws, size_t ws_size,
                              hipStream_t stream) {
    const float* x     = (const float*)d_in[0];   // node_feats f32 [N,128]
    const float* W     = (const float*)d_in[1];
    const float* b     = (const float*)d_in[2];
    const float* Wr    = (const float*)d_in[3];
    const float* br    = (const float*)d_in[4];
    const float* gamma = (const float*)d_in[5];
    const float* beta  = (const float*)d_in[6];
    const int* src = (const int*)d_in[7];
    const int* dst = (const int*)d_in[8];
    float* out = (float*)d_out;

    const int NB1 = (N_NODES + 255) / 256;   // 391 scan blocks

    char* ws = (char*)d_ws;
    size_t off = 0;
    // ---- zeroed prefix (one contiguous memset, ~0.8 MB) ----
    float* gsum    = (float*)(ws + off); off += 512;
    float* gsq     = (float*)(ws + off); off += 512;
    int* cnt_src   = (int*)(ws + off); off += 400128;   // N*4 padded to 256
    int* cnt_dst   = (int*)(ws + off); off += 400128;
    const size_t zero_bytes = off;
    // ---- non-zeroed scratch ----
    int* fill      = (int*)(ws + off); off += 400128;   // zeroed by k_scan1
    int* rowStart  = (int*)(ws + off); off += 400384;   // (N+1)*4 padded
    int* bsum      = (int*)(ws + off); off += 2048;     // NB1*4 padded
    int* esorted   = (int*)(ws + off); off += (size_t)N_EDGES * 4;   // 1.6 MB
    float* c_src   = (float*)(ws + off); off += 400128;
    float* c_dst   = (float*)(ws + off); off += 400128;
    unsigned short* WhiF  = (unsigned short*)(ws + off); off += 32768;
    unsigned short* WloF  = (unsigned short*)(ws + off); off += 32768;
    unsigned short* WrhiF = (unsigned short*)(ws + off); off += 32768;
    unsigned short* WrloF = (unsigned short*)(ws + off); off += 32768;
    const size_t needed = off;   // ~4.3 MB

    if (ws_size < needed) {
        k_zero_out<<<(N_NODES * D / 4 + 255) / 256, 256, 0, stream>>>(out, N_NODES * D / 4);
        return;
    }

    hipMemsetAsync(d_ws, 0, zero_bytes, stream);

    k_make_frags<<<16, 256, 0, stream>>>(W, Wr, WhiF, WloF, WrhiF, WrloF);
    // ---- counting sort of edges by dst ----
    k_count<<<(N_EDGES + 255) / 256, 256, 0, stream>>>(src, dst, cnt_src, cnt_dst);
    k_scan1<<<NB1, 256, 0, stream>>>(cnt_dst, rowStart, bsum, cnt_src, c_src, c_dst, fill);
    k_scan2<<<1, 512, 0, stream>>>(bsum, NB1);
    k_scan3<<<NB1, 256, 0, stream>>>(rowStart, bsum);
    k_fill<<<(N_EDGES + 255) / 256, 256, 0, stream>>>(src, dst, rowStart, fill, esorted);
    // ---- fused gather (chunk-8) + dual GEMM + relu + add + BN partials ----
    k_fused<<<1024, 256, 0, stream>>>(x, esorted, rowStart, c_src, c_dst,
                                      WhiF, WloF, WrhiF, WrloF, b, br, out, gsum, gsq);
    // ---- BN stats + apply (merged) ----
    k_bn_apply<<<2048, 256, 0, stream>>>(out, gsum, gsq, gamma, beta);
}

// Round 15
// 243.665 us; speedup vs baseline: 1.2584x; 1.0219x over previous
//
#include <hip/hip_runtime.h>

#define N_NODES 100000
#define N_EDGES 400000
#define D 128
#define BN_EPS 1e-5f
#define NTILES 6250    // N_NODES/16
#define NINTS 100032   // padded int count of cnt arrays (400128 B)

typedef short short8 __attribute__((ext_vector_type(8)));   // 8 bf16 as raw shorts (4 VGPRs)
typedef float f32x4 __attribute__((ext_vector_type(4)));

static __device__ __forceinline__ float bf2f(unsigned short u) {
    unsigned x = ((unsigned)u) << 16;
    return __builtin_bit_cast(float, x);
}
static __device__ __forceinline__ unsigned short f2bf(float f) {
    unsigned x = __builtin_bit_cast(unsigned, f);
    x += 0x7fffu + ((x >> 16) & 1u);   // round-to-nearest-even
    return (unsigned short)(x >> 16);
}
// split f32 into bf16 hi + bf16 lo (a ~= hi + lo, residual ~2^-17 rel)
static __device__ __forceinline__ void splitbf(float a, short& hi, short& lo) {
    unsigned short h = f2bf(a);
    float r = a - bf2f(h);
    hi = (short)h;
    lo = (short)f2bf(r);
}
static __device__ __forceinline__ void split2(float a, float b, unsigned& hiw, unsigned& low) {
    short ha, la, hb, lb;
    splitbf(a, ha, la);
    splitbf(b, hb, lb);
    hiw = (unsigned)(unsigned short)ha | ((unsigned)(unsigned short)hb << 16);
    low = (unsigned)(unsigned short)la | ((unsigned)(unsigned short)lb << 16);
}
// split 8 f32 (two f32x4) -> uint4 hi-plane + uint4 lo-plane (8 bf16 each)
static __device__ __forceinline__ void split8(f32x4 a, f32x4 b, uint4& hi, uint4& lo) {
    unsigned h0, h1, h2, h3, l0, l1, l2, l3;
    split2(a[0], a[1], h0, l0);
    split2(a[2], a[3], h1, l1);
    split2(b[0], b[1], h2, l2);
    split2(b[2], b[3], h3, l3);
    hi = uint4{h0, h1, h2, h3};
    lo = uint4{l0, l1, l2, l3};
}

// ---------------------------------------------------------------- fallback: clean zero-fill of d_out
__global__ void k_zero_out(float* __restrict__ y, int n4) {
    int t = blockIdx.x * blockDim.x + threadIdx.x;
    if (t < n4) ((float4*)y)[t] = float4{0.f, 0.f, 0.f, 0.f};
}

// ---------------------------------------------------------------- degree histograms
__global__ void k_count(const int* __restrict__ src, const int* __restrict__ dst,
                        int* __restrict__ cnt_src, int* __restrict__ cnt_dst) {
    int t = blockIdx.x * blockDim.x + threadIdx.x;
    if (t >= N_EDGES) return;
    atomicAdd(&cnt_src[src[t]], 1);
    atomicAdd(&cnt_dst[dst[t]], 1);
}

// ---------------------------------------------------------------- W frags + zero count arrays + BN accumulators
// Replaces hipMemsetAsync (r13's coop scan was the regression there, not this merge;
// ordering is stream-safe: this kernel completes before k_count's atomics).
__global__ void k_make_frags(const float* __restrict__ W,
                             const float* __restrict__ Wr,
                             unsigned short* __restrict__ Whi, unsigned short* __restrict__ Wlo,
                             unsigned short* __restrict__ Wrhi, unsigned short* __restrict__ Wrlo,
                             int* __restrict__ cnt_src, int* __restrict__ cnt_dst,
                             float* __restrict__ gsum, float* __restrict__ gsq) {
    int t = blockIdx.x * blockDim.x + threadIdx.x;   // grid 512*256 = 131072
    for (int i = t; i < NINTS; i += 131072) {
        cnt_src[i] = 0;
        cnt_dst[i] = 0;
    }
    if (t < 128) { gsum[t] = 0.f; gsq[t] = 0.f; }
    if (t >= 4096) return;
    int mat = t >> 11;
    int fragIdx = (t >> 6) & 31;
    int lane = t & 63;
    int nt = fragIdx >> 2, ks = fragIdx & 3;
    const float* Wsrc = mat ? Wr : W;
    unsigned short* dhi = mat ? Wrhi : Whi;
    unsigned short* dlo = mat ? Wrlo : Wlo;
    int n = nt * 16 + (lane & 15);
    int kbase = ks * 32 + (lane >> 4) * 8;
    short hi[8], lo[8];
#pragma unroll
    for (int j = 0; j < 8; j++) splitbf(Wsrc[(kbase + j) * D + n], hi[j], lo[j]);
    ((uint4*)dhi)[fragIdx * 64 + lane] = *(uint4*)hi;
    ((uint4*)dlo)[fragIdx * 64 + lane] = *(uint4*)lo;
}

// ---------------------------------------------------------------- exclusive scan level 1 + coeffs (merged)
__global__ void k_scan1(const int* __restrict__ cnt, int* __restrict__ outp,
                        int* __restrict__ bsum,
                        const int* __restrict__ cnt_src,
                        float* __restrict__ c_src, float* __restrict__ c_dst,
                        int* __restrict__ fill) {
    __shared__ int s[256];
    int i = blockIdx.x * 256 + threadIdx.x;
    int v = (i < N_NODES) ? cnt[i] : 0;
    // merged coeffs: rsqrt coefficients + zero the fill cursors
    if (i < N_NODES) {
        c_src[i] = rsqrtf(fmaxf((float)cnt_src[i], 1.0f));
        c_dst[i] = rsqrtf(fmaxf((float)v, 1.0f));
        fill[i] = 0;
    }
    s[threadIdx.x] = v;
    __syncthreads();
    for (int d = 1; d < 256; d <<= 1) {
        int t = (threadIdx.x >= d) ? s[threadIdx.x - d] : 0;
        __syncthreads();
        s[threadIdx.x] += t;
        __syncthreads();
    }
    if (i < N_NODES) outp[i] = s[threadIdx.x] - v;   // exclusive, intra-block only
    if (threadIdx.x == 255) bsum[blockIdx.x] = s[255];
}

// ---------------------------------------------------------------- exclusive scan, level 2 (single block, nb<=512)
__global__ void k_scan2(int* __restrict__ bsum, int nb) {
    __shared__ int s[512];
    int v = (threadIdx.x < nb) ? bsum[threadIdx.x] : 0;
    s[threadIdx.x] = v;
    __syncthreads();
    for (int d = 1; d < 512; d <<= 1) {
        int t = (threadIdx.x >= d) ? s[threadIdx.x - d] : 0;
        __syncthreads();
        s[threadIdx.x] += t;
        __syncthreads();
    }
    if (threadIdx.x < nb) bsum[threadIdx.x] = s[threadIdx.x] - v;
}

// (k_scan3 deleted: consumers add boff[i>>8] at read time — boff is 1.5 KB, L1-hot)

// ---------------------------------------------------------------- bucket-fill: edge srcs sorted by dst
__global__ void k_fill(const int* __restrict__ src, const int* __restrict__ dst,
                       const int* __restrict__ rowStart, const int* __restrict__ boff,
                       int* __restrict__ fill, int* __restrict__ esorted) {
    int e = blockIdx.x * blockDim.x + threadIdx.x;
    if (e >= N_EDGES) return;
    int d = dst[e];
    int pos = rowStart[d] + boff[d >> 8] + atomicAdd(&fill[d], 1);
    esorted[pos] = src[e];
}

// ---------------------------------------------------------------- FUSED gather + dual GEMM  (r12/r14 benched config)
// 77-79 µs, FETCH 127 MB, WRITE 51 MB, VGPR 128, LDS 32768, no spills. Residency is
// VGPR+AGPR-tier-capped at 2 blocks/CU (r7/r12: grid and LDS changes are no-ops).
// Chunk-8 gather, SHORT-LIVED row regs (r9/r10: anything held across MFMA spills).
// Double-buffered A-tile, ONE barrier/tile; direct global epilogue stores.
// Row ranges read as rowStart[n] + boff[n>>8] (scan3 folded away; last node -> N_EDGES).
// DO NOT raise launch_bounds min-waves (r6). DO NOT use cooperative launch (r13).
__global__ __launch_bounds__(256, 2) void k_fused(
    const float* __restrict__ x,
    const int* __restrict__ esorted, const int* __restrict__ rowStart,
    const int* __restrict__ boff,
    const float* __restrict__ c_src, const float* __restrict__ c_dst,
    const unsigned short* __restrict__ Whi, const unsigned short* __restrict__ Wlo,
    const unsigned short* __restrict__ Wrhi, const unsigned short* __restrict__ Wrlo,
    const float* __restrict__ bias_h, const float* __restrict__ bias_r,
    float* __restrict__ yout,
    float* __restrict__ gsum, float* __restrict__ gsq) {
    __shared__ uint4 A[2][16][64];    // 32 KB double-buffered A-tile

    const int wave = threadIdx.x >> 6;
    const int lane = threadIdx.x & 63;
    const int quad = lane >> 4;
    const int l16 = lane & 15;

    // ---- preload this wave's 32-col weight frags into VGPRs (128 VGPR)
    short8 wHf[8], wLf[8], rHf[8], rLf[8];
#pragma unroll
    for (int f = 0; f < 8; f++) {
        int nt = wave * 2 + (f >> 2), ks = f & 3;
        int gi = (nt * 4 + ks) * 64 + lane;
        wHf[f] = __builtin_bit_cast(short8, ((const uint4*)Whi)[gi]);
        wLf[f] = __builtin_bit_cast(short8, ((const uint4*)Wlo)[gi]);
        rHf[f] = __builtin_bit_cast(short8, ((const uint4*)Wrhi)[gi]);
        rLf[f] = __builtin_bit_cast(short8, ((const uint4*)Wrlo)[gi]);
    }
    float bh[2], brr[2];
#pragma unroll
    for (int ntl = 0; ntl < 2; ntl++) {
        int col = wave * 32 + ntl * 16 + l16;
        bh[ntl] = bias_h[col];
        brr[ntl] = bias_r[col];
    }

    float s_acc[2] = {0.f, 0.f}, q_acc[2] = {0.f, 0.f};
    const f32x4* __restrict__ xb = (const f32x4*)x;   // 32 f32x4 per node row

    int buf = 0;
    for (int rt = blockIdx.x; rt < NTILES; rt += gridDim.x, buf ^= 1) {
        const int rowbase = rt * 16;

        // ================= phase A: quad-gather node rowbase + wave*4 + quad (chunk-8)
        {
            const int R = wave * 4 + quad;          // row within tile
            const int n = rowbase + R;
            const int li = l16;                     // feature octet index
            const int beg = rowStart[n] + boff[n >> 8];
            const int end = (n == N_NODES - 1) ? N_EDGES
                            : rowStart[n + 1] + boff[(n + 1) >> 8];
            // residual x-row: issue first so it's in flight under the edge loop
            f32x4 X0 = xb[(size_t)n * 32 + li * 2], X1 = xb[(size_t)n * 32 + li * 2 + 1];
            f32x4 A0 = {0.f, 0.f, 0.f, 0.f}, A1 = {0.f, 0.f, 0.f, 0.f};
            for (int j = beg; j < end; j += 8) {
                int idx[8];
                float c[8];
                f32x4 pa[8], pb[8];
#pragma unroll
                for (int k = 0; k < 8; k++) {
                    int jj = j + k;
                    idx[k] = esorted[(jj < end) ? jj : j];   // dup edge-0 pad (cache hit)
                }
#pragma unroll
                for (int k = 0; k < 8; k++)
                    c[k] = (j + k < end) ? c_src[idx[k]] : 0.f;
                // 16 independent 16B loads in flight -> one HBM latency per round
#pragma unroll
                for (int k = 0; k < 8; k++) {
                    pa[k] = xb[(size_t)idx[k] * 32 + li * 2];
                    pb[k] = xb[(size_t)idx[k] * 32 + li * 2 + 1];
                }
#pragma unroll
                for (int k = 0; k < 8; k++) {
                    A0 += pa[k] * c[k];
                    A1 += pb[k] * c[k];
                }
            }
            float cd = c_dst[n];
            A0 *= cd; A1 *= cd;
            uint4 ahi, alo, xhi, xlo;
            split8(A0, A1, ahi, alo);
            split8(X0, X1, xhi, xlo);
            uint4* Arow = &A[buf][R][0];
            const int sw = li ^ (R & 7);            // bank swizzle
            Arow[sw] = ahi;
            Arow[16 + sw] = alo;
            Arow[32 + sw] = xhi;
            Arow[48 + sw] = xlo;
        }
        __syncthreads();   // A-tile writes visible; double-buffer -> only barrier needed

        // ================= phase B: MFMA from LDS A-tile
        const uint4* rowA = &A[buf][l16][0];
        const int r7 = l16 & 7;
        short8 aH[4], aL[4], xH[4], xL[4];
#pragma unroll
        for (int ks = 0; ks < 4; ks++) {
            const int sl = (ks * 4 + quad) ^ r7;
            aH[ks] = __builtin_bit_cast(short8, rowA[sl]);
            aL[ks] = __builtin_bit_cast(short8, rowA[16 + sl]);
            xH[ks] = __builtin_bit_cast(short8, rowA[32 + sl]);
            xL[ks] = __builtin_bit_cast(short8, rowA[48 + sl]);
        }

        f32x4 accH[2], accR[2];
#pragma unroll
        for (int ntl = 0; ntl < 2; ntl++) {
            accH[ntl] = f32x4{0.f, 0.f, 0.f, 0.f};
            accR[ntl] = f32x4{0.f, 0.f, 0.f, 0.f};
#pragma unroll
            for (int ks = 0; ks < 4; ks++) {
                const int f = ntl * 4 + ks;
                accH[ntl] = __builtin_amdgcn_mfma_f32_16x16x32_bf16(aH[ks], wHf[f], accH[ntl], 0, 0, 0);
                accH[ntl] = __builtin_amdgcn_mfma_f32_16x16x32_bf16(aH[ks], wLf[f], accH[ntl], 0, 0, 0);
                accH[ntl] = __builtin_amdgcn_mfma_f32_16x16x32_bf16(aL[ks], wHf[f], accH[ntl], 0, 0, 0);
                accR[ntl] = __builtin_amdgcn_mfma_f32_16x16x32_bf16(xH[ks], rHf[f], accR[ntl], 0, 0, 0);
                accR[ntl] = __builtin_amdgcn_mfma_f32_16x16x32_bf16(xH[ks], rLf[f], accR[ntl], 0, 0, 0);
                accR[ntl] = __builtin_amdgcn_mfma_f32_16x16x32_bf16(xL[ks], rHf[f], accR[ntl], 0, 0, 0);
            }
        }

        // ---- epilogue: DIRECT global stores from acc + BN partials (no LDS, no waits)
#pragma unroll
        for (int ntl = 0; ntl < 2; ntl++) {
            float s = 0.f, q = 0.f;
#pragma unroll
            for (int r = 0; r < 4; r++) {
                float y = fmaxf(accH[ntl][r] + bh[ntl], 0.f) + fmaxf(accR[ntl][r] + brr[ntl], 0.f);
                yout[(size_t)(rowbase + quad * 4 + r) * D + wave * 32 + ntl * 16 + l16] = y;
                s += y;
                q += y * y;
            }
            s_acc[ntl] += s;
            q_acc[ntl] += q;
        }
        // no trailing barrier: next iter writes A[buf^1]; per-iter barrier keeps all
        // waves within one iteration, so A[buf] reads finish before its next write
    }

    // ---- per-wave stats: quads hold same column set
#pragma unroll
    for (int ntl = 0; ntl < 2; ntl++) {
        float s = s_acc[ntl], q = q_acc[ntl];
        s += __shfl_xor(s, 16, 64);
        s += __shfl_xor(s, 32, 64);
        q += __shfl_xor(q, 16, 64);
        q += __shfl_xor(q, 32, 64);
        if (lane < 16) {
            unsafeAtomicAdd(&gsum[wave * 32 + ntl * 16 + lane], s);
            unsafeAtomicAdd(&gsq[wave * 32 + ntl * 16 + lane], q);
        }
    }
}

// ---------------------------------------------------------------- BN stats + apply, merged
__global__ void k_bn_apply(float* __restrict__ y,
                           const float* __restrict__ gsum, const float* __restrict__ gsq,
                           const float* __restrict__ gamma, const float* __restrict__ beta) {
    __shared__ float sc[128], sh[128];
    if (threadIdx.x < 128) {
        int f = threadIdx.x;
        const float invN = 1.0f / (float)N_NODES;
        float mean = gsum[f] * invN;
        float var = fmaxf(gsq[f] * invN - mean * mean, 0.f);
        float s = gamma[f] * rsqrtf(var + BN_EPS);
        sc[f] = s;
        sh[f] = beta[f] - mean * s;
    }
    __syncthreads();
    const int total4 = N_NODES * D / 4;
    for (int i = blockIdx.x * blockDim.x + threadIdx.x; i < total4; i += gridDim.x * blockDim.x) {
        float4 v = ((float4*)y)[i];
        int f = (i * 4) & (D - 1);
        v.x = v.x * sc[f] + sh[f];
        v.y = v.y * sc[f + 1] + sh[f + 1];
        v.z = v.z * sc[f + 2] + sh[f + 2];
        v.w = v.w * sc[f + 3] + sh[f + 3];
        ((float4*)y)[i] = v;
    }
}

// ---------------------------------------------------------------- launch
extern "C" void kernel_launch(void* const* d_in, const int* in_sizes, int n_in,
                              void* d_out, int out_size, void* d_ws, size_t ws_size,
                              hipStream_t stream) {
    const float* x     = (const float*)d_in[0];   // node_feats f32 [N,128]
    const float* W     = (const float*)d_in[1];
    const float* b     = (const float*)d_in[2];
    const float* Wr    = (const float*)d_in[3];
    const float* br    = (const float*)d_in[4];
    const float* gamma = (const float*)d_in[5];
    const float* beta  = (const float*)d_in[6];
    const int* src = (const int*)d_in[7];
    const int* dst = (const int*)d_in[8];
    float* out = (float*)d_out;

    const int NB1 = (N_NODES + 255) / 256;   // 391 scan blocks

    char* ws = (char*)d_ws;
    size_t off = 0;
    float* gsum    = (float*)(ws + off); off += 512;
    float* gsq     = (float*)(ws + off); off += 512;
    int* cnt_src   = (int*)(ws + off); off += 400128;   // NINTS*4
    int* cnt_dst   = (int*)(ws + off); off += 400128;
    int* fill      = (int*)(ws + off); off += 400128;   // zeroed by k_scan1
    int* rowStart  = (int*)(ws + off); off += 400384;   // (N+1)*4 padded
    int* bsum      = (int*)(ws + off); off += 2048;     // NB1*4 padded
    int* esorted   = (int*)(ws + off); off += (size_t)N_EDGES * 4;   // 1.6 MB
    float* c_src   = (float*)(ws + off); off += 400128;
    float* c_dst   = (float*)(ws + off); off += 400128;
    unsigned short* WhiF  = (unsigned short*)(ws + off); off += 32768;
    unsigned short* WloF  = (unsigned short*)(ws + off); off += 32768;
    unsigned short* WrhiF = (unsigned short*)(ws + off); off += 32768;
    unsigned short* WrloF = (unsigned short*)(ws + off); off += 32768;
    const size_t needed = off;   // ~4.3 MB

    if (ws_size < needed) {
        k_zero_out<<<(N_NODES * D / 4 + 255) / 256, 256, 0, stream>>>(out, N_NODES * D / 4);
        return;
    }

    // 1. weight frags + zero cnt arrays and BN accumulators (replaces hipMemsetAsync)
    k_make_frags<<<512, 256, 0, stream>>>(W, Wr, WhiF, WloF, WrhiF, WrloF,
                                          cnt_src, cnt_dst, gsum, gsq);
    // 2. degree histograms
    k_count<<<(N_EDGES + 255) / 256, 256, 0, stream>>>(src, dst, cnt_src, cnt_dst);
    // 3-4. two-level scan (block-local prefix + block-sum scan; consumers add boff)
    k_scan1<<<NB1, 256, 0, stream>>>(cnt_dst, rowStart, bsum, cnt_src, c_src, c_dst, fill);
    k_scan2<<<1, 512, 0, stream>>>(bsum, NB1);
    // 5. bucket-fill edges by dst (applies boff at read)
    k_fill<<<(N_EDGES + 255) / 256, 256, 0, stream>>>(src, dst, rowStart, bsum, fill, esorted);
    // 6. fused gather (chunk-8) + dual GEMM + relu + add + BN partials
    k_fused<<<1024, 256, 0, stream>>>(x, esorted, rowStart, bsum, c_src, c_dst,
                                      WhiF, WloF, WrhiF, WrloF, b, br, out, gsum, gsq);
    // 7. BN stats + apply (merged)
    k_bn_apply<<<2048, 256, 0, stream>>>(out, gsum, gsq, gamma, beta);
}